// Round 2
// baseline (23168.344 us; speedup 1.0000x reference)
//
#include <hip/hip_runtime.h>
#include <hip/hip_bf16.h>
#include <math.h>

#define BATCH 16
#define KPTS 512
#define LSEQ 1024
#define NDIMS 64
#define HDIM 512
#define NLAYER 12
#define NSTATE 64
#define ICH 1024
#define DTRANK 32
#define EPSF 1e-5f

// wave-wide (64 lane) sum: 4 DPP butterfly stages within rows of 16, then 2 shuffles.
__device__ __forceinline__ float wave_red_sum(float v) {
    int x;
    x = __builtin_amdgcn_update_dpp(0, __float_as_int(v), 0xB1, 0xF, 0xF, true);  // quad_perm [1,0,3,2]
    v += __int_as_float(x);
    x = __builtin_amdgcn_update_dpp(0, __float_as_int(v), 0x4E, 0xF, 0xF, true);  // quad_perm [2,3,0,1]
    v += __int_as_float(x);
    x = __builtin_amdgcn_update_dpp(0, __float_as_int(v), 0x141, 0xF, 0xF, true); // row_half_mirror
    v += __int_as_float(x);
    x = __builtin_amdgcn_update_dpp(0, __float_as_int(v), 0x140, 0xF, 0xF, true); // row_mirror
    v += __int_as_float(x);
    v += __shfl_xor(v, 16);
    v += __shfl_xor(v, 32);
    return v;
}

__device__ __forceinline__ float siluf(float x) {
    return x / (1.f + __expf(-x));
}

// ---------------- embed: tokens -> h [R=16384][512] ----------------
__global__ __launch_bounds__(256) void k_embed(
    const float* __restrict__ xs, const float* __restrict__ ys,
    const float* __restrict__ w, const float* __restrict__ bias,
    float* __restrict__ h)
{
    __shared__ float tok[NDIMS];
    int r = blockIdx.x;              // b*L + t
    int b = r >> 10, t = r & 1023;
    int tid = threadIdx.x;
    float* hrow = h + (size_t)r * HDIM;
    if (t & 1) {
        float yv = ys[b * KPTS + (t >> 1)];
        for (int j = tid; j < HDIM; j += 256)
            hrow[j] = fmaf(yv, w[(size_t)j * NDIMS], bias[j]);
    } else {
        int k = t >> 1;
        if (tid < NDIMS) tok[tid] = xs[((size_t)(b * KPTS + k)) * NDIMS + tid];
        __syncthreads();
        for (int j = tid; j < HDIM; j += 256) {
            const float* wr = w + (size_t)j * NDIMS;
            float acc = bias[j];
            #pragma unroll
            for (int d = 0; d < NDIMS; d += 4) {
                float4 wv = *(const float4*)(wr + d);
                acc = fmaf(tok[d+0], wv.x, acc);
                acc = fmaf(tok[d+1], wv.y, acc);
                acc = fmaf(tok[d+2], wv.z, acc);
                acc = fmaf(tok[d+3], wv.w, acc);
            }
            hrow[j] = acc;
        }
    }
}

// ---------------- rmsnorm: h -> xn ----------------
__global__ __launch_bounds__(256) void k_rmsnorm(
    const float* __restrict__ h, const float* __restrict__ w,
    float* __restrict__ xn)
{
    __shared__ float red[4];
    int r = blockIdx.x;
    int tid = threadIdx.x;
    const float* hr = h + (size_t)r * HDIM;
    float x0 = hr[tid], x1 = hr[tid + 256];
    float v = wave_red_sum(x0*x0 + x1*x1);
    if ((tid & 63) == 0) red[tid >> 6] = v;
    __syncthreads();
    float tot = red[0] + red[1] + red[2] + red[3];
    float scale = rsqrtf(tot * (1.0f / HDIM) + EPSF);
    float* xr = xn + (size_t)r * HDIM;
    xr[tid]       = x0 * scale * w[tid];
    xr[tid + 256] = x1 * scale * w[tid + 256];
}

// ---------------- generic tiled GEMM: C[M,N] (+=) act(A[M,K] * W[N,K]^T + bias) ----------------
// 128x128 tile, BK=16, 256 threads, 8x8 microtile. fp32.
template<int ACT, bool BIAS, bool ACCUM>
__global__ __launch_bounds__(256) void k_gemm(
    const float* __restrict__ A, int lda,
    const float* __restrict__ W,     // [N][K]
    const float* __restrict__ bias,
    float* C, int ldc,
    int N, int K)
{
    __shared__ float As[16][132];
    __shared__ float Ws[16][132];
    int tid = threadIdx.x;
    int m0 = blockIdx.x * 128;
    int n0 = blockIdx.y * 128;
    int tx = tid & 15, ty = tid >> 4;
    int rr = tid >> 1, hf = (tid & 1) * 8;
    float acc[8][8];
    #pragma unroll
    for (int i = 0; i < 8; ++i)
        #pragma unroll
        for (int j = 0; j < 8; ++j) acc[i][j] = 0.f;

    for (int k0 = 0; k0 < K; k0 += 16) {
        const float* ap = A + (size_t)(m0 + rr) * lda + k0 + hf;
        float4 a0 = *(const float4*)ap;
        float4 a1 = *(const float4*)(ap + 4);
        As[hf+0][rr] = a0.x; As[hf+1][rr] = a0.y; As[hf+2][rr] = a0.z; As[hf+3][rr] = a0.w;
        As[hf+4][rr] = a1.x; As[hf+5][rr] = a1.y; As[hf+6][rr] = a1.z; As[hf+7][rr] = a1.w;
        int n = n0 + rr;
        if (n < N) {
            const float* wp = W + (size_t)n * K + k0 + hf;
            float4 w0 = *(const float4*)wp;
            float4 w1 = *(const float4*)(wp + 4);
            Ws[hf+0][rr] = w0.x; Ws[hf+1][rr] = w0.y; Ws[hf+2][rr] = w0.z; Ws[hf+3][rr] = w0.w;
            Ws[hf+4][rr] = w1.x; Ws[hf+5][rr] = w1.y; Ws[hf+6][rr] = w1.z; Ws[hf+7][rr] = w1.w;
        } else {
            #pragma unroll
            for (int j = 0; j < 8; ++j) Ws[hf+j][rr] = 0.f;
        }
        __syncthreads();
        #pragma unroll
        for (int kk = 0; kk < 16; ++kk) {
            float4 av0 = *(const float4*)&As[kk][ty*8];
            float4 av1 = *(const float4*)&As[kk][ty*8+4];
            float4 bv0 = *(const float4*)&Ws[kk][tx*8];
            float4 bv1 = *(const float4*)&Ws[kk][tx*8+4];
            float av[8] = {av0.x,av0.y,av0.z,av0.w,av1.x,av1.y,av1.z,av1.w};
            float bv[8] = {bv0.x,bv0.y,bv0.z,bv0.w,bv1.x,bv1.y,bv1.z,bv1.w};
            #pragma unroll
            for (int i = 0; i < 8; ++i)
                #pragma unroll
                for (int j = 0; j < 8; ++j)
                    acc[i][j] = fmaf(av[i], bv[j], acc[i][j]);
        }
        __syncthreads();
    }
    #pragma unroll
    for (int i = 0; i < 8; ++i) {
        int m = m0 + ty*8 + i;
        float* crow = C + (size_t)m * ldc;
        #pragma unroll
        for (int j = 0; j < 8; ++j) {
            int n = n0 + tx*8 + j;
            if (n < N) {
                float v = acc[i][j];
                if (BIAS) v += bias[n];
                if (ACT == 1) v = (v > 15.f) ? v : log1pf(__expf(v));  // softplus
                if (ACCUM) crow[n] += v; else crow[n] = v;
            }
        }
    }
}

// ---------------- causal depthwise conv (K=4) + silu: proj[:, :1024] -> u ----------------
__global__ __launch_bounds__(256) void k_conv(
    const float* __restrict__ proj,   // [R][2048], u_raw in cols 0..1023
    const float* __restrict__ cw,     // [1024][4]
    const float* __restrict__ cb,     // [1024]
    float* __restrict__ u)            // [R][1024]
{
    int idx = blockIdx.x * 256 + threadIdx.x;
    int i = idx & 1023;
    int r = idx >> 10;
    int t = r & 1023;
    float4 wv = *(const float4*)(cw + (size_t)i * 4);
    float wk[4] = {wv.x, wv.y, wv.z, wv.w};
    float acc = cb[i];
    #pragma unroll
    for (int k = 0; k < 4; ++k) {
        int tt = t + k - 3;
        if (tt >= 0)
            acc = fmaf(proj[((size_t)(r + k - 3)) * 2048 + i], wk[k], acc);
    }
    u[(size_t)r * 1024 + i] = siluf(acc);
}

// ---------------- selective scan: one wave per (b,i); dt read in-place, y written in-place ----------------
__global__ __launch_bounds__(256) void k_scan(
    float* dty,                        // proj base: dt at [r*2048+i] on input, y on output (stride 2048)
    const float* __restrict__ u,       // [R][1024]
    const float* __restrict__ ssm,     // [R][160]: [32:96]=B, [96:160]=C
    const float* __restrict__ A_log)   // [1024][64]
{
    int gw = (blockIdx.x * 256 + threadIdx.x) >> 6;   // b*1024 + i
    int lane = threadIdx.x & 63;
    int b = gw >> 10, i = gw & 1023;
    float An = -__expf(A_log[(size_t)i * 64 + lane]);
    size_t rb = (size_t)b * 1024;
    float* dtp      = dty + rb * 2048 + i;
    const float* up = u   + rb * 1024 + i;
    const float* Bp = ssm + rb * 160 + 32 + lane;
    const float* Cp = ssm + rb * 160 + 96 + lane;
    float s = 0.f;
    for (int t = 0; t < 1024; ++t) {
        float dtv = dtp[(size_t)t * 2048];
        float uv  = up [(size_t)t * 1024];
        float Bv  = Bp [(size_t)t * 160];
        float Cv  = Cp [(size_t)t * 160];
        float dA = __expf(dtv * An);
        s = fmaf(dA, s, dtv * uv * Bv);
        float p = wave_red_sum(s * Cv);
        if (lane == 0) dtp[(size_t)t * 2048] = p;
    }
}

// ---------------- gating: y = (y + u*D) * silu(gate), in place in proj cols 0..1023 ----------------
__global__ __launch_bounds__(256) void k_gate(
    float* proj,
    const float* __restrict__ u,
    const float* __restrict__ Dp)
{
    int idx = blockIdx.x * 256 + threadIdx.x;
    int i = idx & 1023;
    size_t r = (size_t)(idx >> 10);
    float y  = proj[r * 2048 + i];
    float g  = proj[r * 2048 + 1024 + i];
    float uv = u[r * 1024 + i];
    float val = fmaf(uv, Dp[i], y);
    proj[r * 2048 + i] = val * siluf(g);
}

// ---------------- final rmsnorm + readout at even tokens ----------------
__global__ __launch_bounds__(256) void k_head(
    const float* __restrict__ h,
    const float* __restrict__ nfw,
    const float* __restrict__ row_w,
    const float* __restrict__ row_b,
    float* __restrict__ out)
{
    __shared__ float red1[4], red2[4];
    int bk = blockIdx.x;               // b*512 + k
    int b = bk >> 9, k = bk & 511;
    size_t r = (size_t)b * 1024 + 2 * k;
    const float* hr = h + r * HDIM;
    int tid = threadIdx.x;
    float x0 = hr[tid], x1 = hr[tid + 256];
    float v = wave_red_sum(x0*x0 + x1*x1);
    if ((tid & 63) == 0) red1[tid >> 6] = v;
    __syncthreads();
    float tot = red1[0] + red1[1] + red1[2] + red1[3];
    float scale = rsqrtf(tot * (1.f / HDIM) + EPSF);
    float p = x0 * scale * nfw[tid]     * row_w[tid]
            + x1 * scale * nfw[tid+256] * row_w[tid+256];
    p = wave_red_sum(p);
    if ((tid & 63) == 0) red2[tid >> 6] = p;
    __syncthreads();
    if (tid == 0) {
        float res = red2[0] + red2[1] + red2[2] + red2[3] + row_b[0];
        out[bk] = res;
    }
}

extern "C" void kernel_launch(void* const* d_in, const int* in_sizes, int n_in,
                              void* d_out, int out_size, void* d_ws, size_t ws_size,
                              hipStream_t stream)
{
    const float* xs        = (const float*)d_in[0];
    const float* ys        = (const float*)d_in[1];
    const float* read_in_w = (const float*)d_in[2];
    const float* read_in_b = (const float*)d_in[3];
    const float* norm_w    = (const float*)d_in[4];
    const float* in_proj_w = (const float*)d_in[5];
    const float* conv_w    = (const float*)d_in[6];
    const float* conv_b    = (const float*)d_in[7];
    const float* x_proj_w  = (const float*)d_in[8];
    const float* dt_proj_w = (const float*)d_in[9];
    const float* dt_proj_b = (const float*)d_in[10];
    const float* A_log     = (const float*)d_in[11];
    const float* Dvec      = (const float*)d_in[12];
    const float* out_proj_w= (const float*)d_in[13];
    const float* norm_f_w  = (const float*)d_in[14];
    const float* read_out_w= (const float*)d_in[15];
    const float* read_out_b= (const float*)d_in[16];

    // ws layout (fp32 elements), 256 MB total:
    //   h    @ 0         (8388608)   [16384][512]
    //   xn   @ 8388608   (8388608)   [16384][512]   (ssm overlays this region: [16384][160])
    //   proj @ 16777216  (33554432)  [16384][2048]  (dt and then y live in cols 0..1023)
    //   u    @ 50331648  (16777216)  [16384][1024]
    if (ws_size < (size_t)67108864 * 4) return;
    float* ws   = (float*)d_ws;
    float* h    = ws;
    float* xn   = ws + 8388608;
    float* ssm  = xn;                       // alias: xn dead once in_proj GEMM has consumed it
    float* proj = ws + 16777216;
    float* u    = ws + 50331648;

    const int R = BATCH * LSEQ;             // 16384

    k_embed<<<R, 256, 0, stream>>>(xs, ys, read_in_w, read_in_b, h);

    for (int l = 0; l < NLAYER; ++l) {
        const float* nw  = norm_w    + (size_t)l * HDIM;
        const float* ipw = in_proj_w + (size_t)l * 2048 * 512;
        const float* cw  = conv_w    + (size_t)l * 1024 * 4;
        const float* cb  = conv_b    + (size_t)l * 1024;
        const float* xpw = x_proj_w  + (size_t)l * 160 * 1024;
        const float* dpw = dt_proj_w + (size_t)l * 1024 * 32;
        const float* dpb = dt_proj_b + (size_t)l * 1024;
        const float* al  = A_log     + (size_t)l * 1024 * 64;
        const float* dv  = Dvec      + (size_t)l * 1024;
        const float* opw = out_proj_w+ (size_t)l * 512 * 1024;

        k_rmsnorm<<<R, 256, 0, stream>>>(h, nw, xn);

        dim3 g1(R/128, 2048/128);
        k_gemm<0,false,false><<<g1, 256, 0, stream>>>(xn, HDIM, ipw, nullptr, proj, 2048, 2048, HDIM);

        k_conv<<<(R*1024)/256, 256, 0, stream>>>(proj, cw, cb, u);

        dim3 g2(R/128, 2);                   // N=160 -> 2 column tiles
        k_gemm<0,false,false><<<g2, 256, 0, stream>>>(u, 1024, xpw, nullptr, ssm, 160, 160, 1024);

        dim3 g3(R/128, 1024/128);            // dt written into proj cols 0..1023 (stride 2048)
        k_gemm<1,true,false><<<g3, 256, 0, stream>>>(ssm, 160, dpw, dpb, proj, 2048, 1024, DTRANK);

        k_scan<<<(BATCH*1024)/4, 256, 0, stream>>>(proj, u, ssm, al);

        k_gate<<<(R*1024)/256, 256, 0, stream>>>(proj, u, dv);

        dim3 g4(R/128, 512/128);
        k_gemm<0,false,true><<<g4, 256, 0, stream>>>(proj, 2048, opw, nullptr, h, HDIM, HDIM, 1024);
    }

    k_head<<<BATCH*KPTS, 256, 0, stream>>>(h, norm_f_w, read_out_w, read_out_b, (float*)d_out);
}

// Round 3
// 8413.811 us; speedup vs baseline: 2.7536x; 2.7536x over previous
//
#include <hip/hip_runtime.h>
#include <hip/hip_bf16.h>
#include <math.h>

#define BATCH 16
#define KPTS 512
#define LSEQ 1024
#define NDIMS 64
#define HDIM 512
#define NLAYER 12
#define NSTATE 64
#define ICH 1024
#define DTRANK 32
#define EPSF 1e-5f

using f32x4  = __attribute__((ext_vector_type(4))) float;
using bf16x8 = __attribute__((ext_vector_type(8))) short;

// fp32 -> bf16 RNE (manual, no API dependence)
__device__ __forceinline__ unsigned short f2b(float f) {
    unsigned int u = __float_as_uint(f);
    unsigned int r = (u + 0x7FFFu + ((u >> 16) & 1u)) >> 16;
    return (unsigned short)r;
}

// wave-wide (64 lane) sum
__device__ __forceinline__ float wave_red_sum(float v) {
    int x;
    x = __builtin_amdgcn_update_dpp(0, __float_as_int(v), 0xB1, 0xF, 0xF, true);
    v += __int_as_float(x);
    x = __builtin_amdgcn_update_dpp(0, __float_as_int(v), 0x4E, 0xF, 0xF, true);
    v += __int_as_float(x);
    x = __builtin_amdgcn_update_dpp(0, __float_as_int(v), 0x141, 0xF, 0xF, true);
    v += __int_as_float(x);
    x = __builtin_amdgcn_update_dpp(0, __float_as_int(v), 0x140, 0xF, 0xF, true);
    v += __int_as_float(x);
    v += __shfl_xor(v, 16);
    v += __shfl_xor(v, 32);
    return v;
}

// 16-lane-row sum (all 16 lanes end with the row total)
__device__ __forceinline__ float red16(float v) {
    int x;
    x = __builtin_amdgcn_update_dpp(0, __float_as_int(v), 0xB1, 0xF, 0xF, true);
    v += __int_as_float(x);
    x = __builtin_amdgcn_update_dpp(0, __float_as_int(v), 0x4E, 0xF, 0xF, true);
    v += __int_as_float(x);
    x = __builtin_amdgcn_update_dpp(0, __float_as_int(v), 0x141, 0xF, 0xF, true);
    v += __int_as_float(x);
    x = __builtin_amdgcn_update_dpp(0, __float_as_int(v), 0x140, 0xF, 0xF, true);
    v += __int_as_float(x);
    return v;
}

__device__ __forceinline__ float siluf(float x) {
    return x / (1.f + __expf(-x));
}

// ---------------- embed ----------------
__global__ __launch_bounds__(256) void k_embed(
    const float* __restrict__ xs, const float* __restrict__ ys,
    const float* __restrict__ w, const float* __restrict__ bias,
    float* __restrict__ h)
{
    __shared__ float tok[NDIMS];
    int r = blockIdx.x;
    int b = r >> 10, t = r & 1023;
    int tid = threadIdx.x;
    float* hrow = h + (size_t)r * HDIM;
    if (t & 1) {
        float yv = ys[b * KPTS + (t >> 1)];
        for (int j = tid; j < HDIM; j += 256)
            hrow[j] = fmaf(yv, w[(size_t)j * NDIMS], bias[j]);
    } else {
        int k = t >> 1;
        if (tid < NDIMS) tok[tid] = xs[((size_t)(b * KPTS + k)) * NDIMS + tid];
        __syncthreads();
        for (int j = tid; j < HDIM; j += 256) {
            const float* wr = w + (size_t)j * NDIMS;
            float acc = bias[j];
            #pragma unroll
            for (int d = 0; d < NDIMS; d += 4) {
                float4 wv = *(const float4*)(wr + d);
                acc = fmaf(tok[d+0], wv.x, acc);
                acc = fmaf(tok[d+1], wv.y, acc);
                acc = fmaf(tok[d+2], wv.z, acc);
                acc = fmaf(tok[d+3], wv.w, acc);
            }
            hrow[j] = acc;
        }
    }
}

// ---------------- rmsnorm: h -> xn (bf16) ----------------
__global__ __launch_bounds__(256) void k_rmsnorm(
    const float* __restrict__ h, const float* __restrict__ w,
    unsigned short* __restrict__ xn)
{
    __shared__ float red[4];
    int r = blockIdx.x;
    int tid = threadIdx.x;
    const float* hr = h + (size_t)r * HDIM;
    float x0 = hr[tid], x1 = hr[tid + 256];
    float v = wave_red_sum(x0*x0 + x1*x1);
    if ((tid & 63) == 0) red[tid >> 6] = v;
    __syncthreads();
    float tot = red[0] + red[1] + red[2] + red[3];
    float scale = rsqrtf(tot * (1.0f / HDIM) + EPSF);
    unsigned short* xr = xn + (size_t)r * HDIM;
    xr[tid]       = f2b(x0 * scale * w[tid]);
    xr[tid + 256] = f2b(x1 * scale * w[tid + 256]);
}

// ---------------- per-layer weight convert fp32 -> bf16 ----------------
// wbuf layout (u16): in_w [0,1048576) ; x_w [1048576,1212416) ; out_w [1212416,1736704)
__global__ __launch_bounds__(256) void k_wcvt(
    const float* __restrict__ iw, const float* __restrict__ xw,
    const float* __restrict__ ow, unsigned short* __restrict__ wb)
{
    int idx = blockIdx.x * 256 + threadIdx.x;     // one float4 each
    const float* src; unsigned short* dst; int off;
    if (idx < 262144)            { src = iw; dst = wb;            off = idx; }
    else if (idx < 303104)       { src = xw; dst = wb + 1048576;  off = idx - 262144; }
    else                         { src = ow; dst = wb + 1212416;  off = idx - 303104; }
    float4 f = *(const float4*)(src + (size_t)off * 4);
    ushort4 o;
    o.x = f2b(f.x); o.y = f2b(f.y); o.z = f2b(f.z); o.w = f2b(f.w);
    *(ushort4*)(dst + (size_t)off * 4) = o;
}

// ---------------- MFMA GEMM: C[M,N] (+=) A[M,K] * W[N,K]^T ----------------
// 128x128 tile, BK=64, 4 waves (2x2), mfma_f32_16x16x32_bf16.
// A: bf16 [M][lda] (AFP32=false) or fp32 [M][lda] converted in staging.
template<bool AFP32, bool ACCUM, bool NG>
__global__ __launch_bounds__(256) void k_mgemm(
    const void* __restrict__ Aptr, int lda,
    const unsigned short* __restrict__ W,   // bf16 [N][K]
    float* __restrict__ C, int ldc, int N, int K)
{
    __shared__ unsigned short As[128 * 72];   // row stride 144B -> 2-way (free)
    __shared__ unsigned short Ws[128 * 72];
    int tid  = threadIdx.x;
    int m0   = blockIdx.x * 128, n0 = blockIdx.y * 128;
    int wave = tid >> 6, lane = tid & 63;
    int wr   = (wave >> 1) * 64, wc = (wave & 1) * 64;
    int lr   = lane & 15, lq = lane >> 4;
    int srow = tid >> 1, sseg = (tid & 1) * 32;

    f32x4 acc[4][4];
    #pragma unroll
    for (int m = 0; m < 4; ++m)
        #pragma unroll
        for (int n = 0; n < 4; ++n)
            acc[m][n] = (f32x4){0.f, 0.f, 0.f, 0.f};

    int wn = n0 + srow;
    bool wok = (!NG) || (wn < N);
    const unsigned short* wg0 = W + (size_t)(wok ? wn : 0) * K;

    for (int k0 = 0; k0 < K; k0 += 64) {
        uint4 aw[4];
        if (!AFP32) {
            const unsigned short* ag = (const unsigned short*)Aptr + (size_t)(m0 + srow) * lda + k0 + sseg;
            aw[0] = *(const uint4*)(ag);
            aw[1] = *(const uint4*)(ag + 8);
            aw[2] = *(const uint4*)(ag + 16);
            aw[3] = *(const uint4*)(ag + 24);
        } else {
            const float* ag = (const float*)Aptr + (size_t)(m0 + srow) * lda + k0 + sseg;
            unsigned short us[32];
            #pragma unroll
            for (int j = 0; j < 8; ++j) {
                float4 f = *(const float4*)(ag + j * 4);
                us[j*4+0] = f2b(f.x); us[j*4+1] = f2b(f.y);
                us[j*4+2] = f2b(f.z); us[j*4+3] = f2b(f.w);
            }
            aw[0] = *(uint4*)&us[0];  aw[1] = *(uint4*)&us[8];
            aw[2] = *(uint4*)&us[16]; aw[3] = *(uint4*)&us[24];
        }
        uint4 ww[4];
        if (wok) {
            const unsigned short* wg = wg0 + k0 + sseg;
            ww[0] = *(const uint4*)(wg);
            ww[1] = *(const uint4*)(wg + 8);
            ww[2] = *(const uint4*)(wg + 16);
            ww[3] = *(const uint4*)(wg + 24);
        } else {
            ww[0] = make_uint4(0,0,0,0); ww[1] = make_uint4(0,0,0,0);
            ww[2] = make_uint4(0,0,0,0); ww[3] = make_uint4(0,0,0,0);
        }
        __syncthreads();                       // prev compute done
        unsigned short* ap = &As[srow * 72 + sseg];
        *(uint4*)(ap)      = aw[0]; *(uint4*)(ap + 8)  = aw[1];
        *(uint4*)(ap + 16) = aw[2]; *(uint4*)(ap + 24) = aw[3];
        unsigned short* wp = &Ws[srow * 72 + sseg];
        *(uint4*)(wp)      = ww[0]; *(uint4*)(wp + 8)  = ww[1];
        *(uint4*)(wp + 16) = ww[2]; *(uint4*)(wp + 24) = ww[3];
        __syncthreads();                       // tiles ready
        #pragma unroll
        for (int kk = 0; kk < 2; ++kk) {
            bf16x8 af[4], bfr[4];
            #pragma unroll
            for (int f = 0; f < 4; ++f)
                af[f] = *(const bf16x8*)&As[(wr + f*16 + lr) * 72 + kk*32 + lq*8];
            #pragma unroll
            for (int f = 0; f < 4; ++f)
                bfr[f] = *(const bf16x8*)&Ws[(wc + f*16 + lr) * 72 + kk*32 + lq*8];
            #pragma unroll
            for (int m = 0; m < 4; ++m)
                #pragma unroll
                for (int n = 0; n < 4; ++n)
                    acc[m][n] = __builtin_amdgcn_mfma_f32_16x16x32_bf16(af[m], bfr[n], acc[m][n], 0, 0, 0);
        }
    }
    // epilogue: C/D frag: col = lane&15, row = (lane>>4)*4 + reg
    #pragma unroll
    for (int m = 0; m < 4; ++m) {
        int row = m0 + wr + m*16 + lq*4;
        #pragma unroll
        for (int n = 0; n < 4; ++n) {
            int col = n0 + wc + n*16 + lr;
            if ((!NG) || col < N) {
                float* cp = C + (size_t)row * ldc + col;
                #pragma unroll
                for (int r = 0; r < 4; ++r) {
                    float v = acc[m][n][r];
                    if (ACCUM) cp[(size_t)r * ldc] += v;
                    else       cp[(size_t)r * ldc] = v;
                }
            }
        }
    }
}

// ---------------- old fp32 tiled GEMM (kept for dt_proj, K=32, softplus) ----------------
template<int ACT, bool BIAS, bool ACCUM>
__global__ __launch_bounds__(256) void k_gemm(
    const float* __restrict__ A, int lda,
    const float* __restrict__ W,     // [N][K]
    const float* __restrict__ bias,
    float* C, int ldc, int N, int K)
{
    __shared__ float As[16][132];
    __shared__ float Wsh[16][132];
    int tid = threadIdx.x;
    int m0 = blockIdx.x * 128;
    int n0 = blockIdx.y * 128;
    int tx = tid & 15, ty = tid >> 4;
    int rr = tid >> 1, hf = (tid & 1) * 8;
    float acc[8][8];
    #pragma unroll
    for (int i = 0; i < 8; ++i)
        #pragma unroll
        for (int j = 0; j < 8; ++j) acc[i][j] = 0.f;

    for (int k0 = 0; k0 < K; k0 += 16) {
        const float* ap = A + (size_t)(m0 + rr) * lda + k0 + hf;
        float4 a0 = *(const float4*)ap;
        float4 a1 = *(const float4*)(ap + 4);
        As[hf+0][rr] = a0.x; As[hf+1][rr] = a0.y; As[hf+2][rr] = a0.z; As[hf+3][rr] = a0.w;
        As[hf+4][rr] = a1.x; As[hf+5][rr] = a1.y; As[hf+6][rr] = a1.z; As[hf+7][rr] = a1.w;
        int n = n0 + rr;
        if (n < N) {
            const float* wp = W + (size_t)n * K + k0 + hf;
            float4 w0 = *(const float4*)wp;
            float4 w1 = *(const float4*)(wp + 4);
            Wsh[hf+0][rr] = w0.x; Wsh[hf+1][rr] = w0.y; Wsh[hf+2][rr] = w0.z; Wsh[hf+3][rr] = w0.w;
            Wsh[hf+4][rr] = w1.x; Wsh[hf+5][rr] = w1.y; Wsh[hf+6][rr] = w1.z; Wsh[hf+7][rr] = w1.w;
        } else {
            #pragma unroll
            for (int j = 0; j < 8; ++j) Wsh[hf+j][rr] = 0.f;
        }
        __syncthreads();
        #pragma unroll
        for (int kk = 0; kk < 16; ++kk) {
            float4 av0 = *(const float4*)&As[kk][ty*8];
            float4 av1 = *(const float4*)&As[kk][ty*8+4];
            float4 bv0 = *(const float4*)&Wsh[kk][tx*8];
            float4 bv1 = *(const float4*)&Wsh[kk][tx*8+4];
            float av[8] = {av0.x,av0.y,av0.z,av0.w,av1.x,av1.y,av1.z,av1.w};
            float bv[8] = {bv0.x,bv0.y,bv0.z,bv0.w,bv1.x,bv1.y,bv1.z,bv1.w};
            #pragma unroll
            for (int i = 0; i < 8; ++i)
                #pragma unroll
                for (int j = 0; j < 8; ++j)
                    acc[i][j] = fmaf(av[i], bv[j], acc[i][j]);
        }
        __syncthreads();
    }
    #pragma unroll
    for (int i = 0; i < 8; ++i) {
        int m = m0 + ty*8 + i;
        float* crow = C + (size_t)m * ldc;
        #pragma unroll
        for (int j = 0; j < 8; ++j) {
            int n = n0 + tx*8 + j;
            if (n < N) {
                float v = acc[i][j];
                if (BIAS) v += bias[n];
                if (ACT == 1) v = (v > 15.f) ? v : log1pf(__expf(v));
                if (ACCUM) crow[n] += v; else crow[n] = v;
            }
        }
    }
}

// ---------------- causal depthwise conv (K=4) + silu ----------------
__global__ __launch_bounds__(256) void k_conv(
    const float* __restrict__ proj,
    const float* __restrict__ cw,
    const float* __restrict__ cb,
    float* __restrict__ u)
{
    int idx = blockIdx.x * 256 + threadIdx.x;
    int i = idx & 1023;
    int r = idx >> 10;
    int t = r & 1023;
    float4 wv = *(const float4*)(cw + (size_t)i * 4);
    float wk[4] = {wv.x, wv.y, wv.z, wv.w};
    float acc = cb[i];
    #pragma unroll
    for (int k = 0; k < 4; ++k) {
        int tt = t + k - 3;
        if (tt >= 0)
            acc = fmaf(proj[((size_t)(r + k - 3)) * 2048 + i], wk[k], acc);
    }
    u[(size_t)r * 1024 + i] = siluf(acc);
}

// ---------------- selective scan v2: chunked LDS, 4 states/lane, 4 ch/wave ----------------
// block = 512 thr = 8 waves = 32 channels of one batch; 16 chunks of 64 t.
__global__ __launch_bounds__(512) void k_scan2(
    float* __restrict__ dty,            // proj base: dt in, y out at [r*2048 + i]
    const float* __restrict__ u,        // [R][1024]
    const float* __restrict__ ssm,      // [R][160]: B at +32, C at +96
    const float* __restrict__ A_log)    // [1024][64]
{
    __shared__ float dt_s[64][32];
    __shared__ float u_s [64][32];
    __shared__ float bc_s[64][128];     // B | C
    __shared__ float y_s [64][32];
    int tid = threadIdx.x;
    int blk = blockIdx.x;               // 512 blocks
    int b   = blk >> 5;
    int i0  = (blk & 31) * 32;
    int lane = tid & 63;
    int c  = lane >> 4, nq = lane & 15;
    int ch = (tid >> 6) * 4 + c;        // 0..31
    int i  = i0 + ch;
    size_t rb = (size_t)b * 1024;

    float4 al = *(const float4*)(A_log + (size_t)i * 64 + nq * 4);
    float An0 = -__expf(al.x), An1 = -__expf(al.y), An2 = -__expf(al.z), An3 = -__expf(al.w);
    float s0 = 0.f, s1 = 0.f, s2 = 0.f, s3 = 0.f;

    int st_t = tid >> 3, st_j = tid & 7;
    float*       dt_g = dty + (rb + st_t) * 2048 + i0 + st_j * 4;
    const float* u_g  = u   + (rb + st_t) * 1024 + i0 + st_j * 4;
    const float* bc_g = ssm + (rb + st_t) * 160 + 32 + st_j * 16;

    for (int t0 = 0; t0 < 1024; t0 += 64) {
        float4 rdt = *(const float4*)(dt_g + (size_t)t0 * 2048);
        float4 ru  = *(const float4*)(u_g  + (size_t)t0 * 1024);
        float4 r0  = *(const float4*)(bc_g + (size_t)t0 * 160);
        float4 r1  = *(const float4*)(bc_g + (size_t)t0 * 160 + 4);
        float4 r2  = *(const float4*)(bc_g + (size_t)t0 * 160 + 8);
        float4 r3  = *(const float4*)(bc_g + (size_t)t0 * 160 + 12);
        __syncthreads();                 // prev compute + y_s drain done
        *(float4*)&dt_s[st_t][st_j * 4] = rdt;
        *(float4*)&u_s [st_t][st_j * 4] = ru;
        *(float4*)&bc_s[st_t][st_j * 16]      = r0;
        *(float4*)&bc_s[st_t][st_j * 16 + 4]  = r1;
        *(float4*)&bc_s[st_t][st_j * 16 + 8]  = r2;
        *(float4*)&bc_s[st_t][st_j * 16 + 12] = r3;
        __syncthreads();                 // tiles ready
        #pragma unroll 4
        for (int tt = 0; tt < 64; ++tt) {
            float dtv = dt_s[tt][ch];
            float uv  = u_s [tt][ch];
            float4 Bv = *(const float4*)&bc_s[tt][nq * 4];
            float4 Cv = *(const float4*)&bc_s[tt][64 + nq * 4];
            float du = dtv * uv;
            s0 = fmaf(__expf(dtv * An0), s0, du * Bv.x);
            s1 = fmaf(__expf(dtv * An1), s1, du * Bv.y);
            s2 = fmaf(__expf(dtv * An2), s2, du * Bv.z);
            s3 = fmaf(__expf(dtv * An3), s3, du * Bv.w);
            float p = (s0 * Cv.x + s1 * Cv.y) + (s2 * Cv.z + s3 * Cv.w);
            p = red16(p);
            if (nq == 0) y_s[tt][ch] = p;
        }
        __syncthreads();                 // y chunk complete
        *(float4*)(dt_g + (size_t)t0 * 2048) = *(float4*)&y_s[st_t][st_j * 4];
    }
}

// ---------------- gating ----------------
__global__ __launch_bounds__(256) void k_gate(
    float* proj,
    const float* __restrict__ u,
    const float* __restrict__ Dp)
{
    int idx = blockIdx.x * 256 + threadIdx.x;
    int i = idx & 1023;
    size_t r = (size_t)(idx >> 10);
    float y  = proj[r * 2048 + i];
    float g  = proj[r * 2048 + 1024 + i];
    float uv = u[r * 1024 + i];
    float val = fmaf(uv, Dp[i], y);
    proj[r * 2048 + i] = val * siluf(g);
}

// ---------------- final rmsnorm + readout ----------------
__global__ __launch_bounds__(256) void k_head(
    const float* __restrict__ h,
    const float* __restrict__ nfw,
    const float* __restrict__ row_w,
    const float* __restrict__ row_b,
    float* __restrict__ out)
{
    __shared__ float red1[4], red2[4];
    int bk = blockIdx.x;
    int b = bk >> 9, k = bk & 511;
    size_t r = (size_t)b * 1024 + 2 * k;
    const float* hr = h + r * HDIM;
    int tid = threadIdx.x;
    float x0 = hr[tid], x1 = hr[tid + 256];
    float v = wave_red_sum(x0*x0 + x1*x1);
    if ((tid & 63) == 0) red1[tid >> 6] = v;
    __syncthreads();
    float tot = red1[0] + red1[1] + red1[2] + red1[3];
    float scale = rsqrtf(tot * (1.f / HDIM) + EPSF);
    float p = x0 * scale * nfw[tid]     * row_w[tid]
            + x1 * scale * nfw[tid+256] * row_w[tid+256];
    p = wave_red_sum(p);
    if ((tid & 63) == 0) red2[tid >> 6] = p;
    __syncthreads();
    if (tid == 0) {
        float res = red2[0] + red2[1] + red2[2] + red2[3] + row_b[0];
        out[bk] = res;
    }
}

extern "C" void kernel_launch(void* const* d_in, const int* in_sizes, int n_in,
                              void* d_out, int out_size, void* d_ws, size_t ws_size,
                              hipStream_t stream)
{
    const float* xs        = (const float*)d_in[0];
    const float* ys        = (const float*)d_in[1];
    const float* read_in_w = (const float*)d_in[2];
    const float* read_in_b = (const float*)d_in[3];
    const float* norm_w    = (const float*)d_in[4];
    const float* in_proj_w = (const float*)d_in[5];
    const float* conv_w    = (const float*)d_in[6];
    const float* conv_b    = (const float*)d_in[7];
    const float* x_proj_w  = (const float*)d_in[8];
    const float* dt_proj_w = (const float*)d_in[9];
    const float* dt_proj_b = (const float*)d_in[10];
    const float* A_log     = (const float*)d_in[11];
    const float* Dvec      = (const float*)d_in[12];
    const float* out_proj_w= (const float*)d_in[13];
    const float* norm_f_w  = (const float*)d_in[14];
    const float* read_out_w= (const float*)d_in[15];
    const float* read_out_b= (const float*)d_in[16];

    // ws layout (fp32 element offsets), ~268 MB total:
    //   h    @ 0         [16384][512] f32
    //   ssm  @ 8388608   [16384][160] f32      (2621440 floats)
    //   xnb  @ 11010048  [16384][512] bf16     (4194304 floats of space)
    //   wbuf @ 15204352  1736704 u16           (868352 floats of space)
    //   proj @ 16777216  [16384][2048] f32     (dt -> y in cols 0..1023)
    //   u    @ 50331648  [16384][1024] f32
    if (ws_size < (size_t)67108864 * 4) return;
    float* ws = (float*)d_ws;
    float* h    = ws;
    float* ssm  = ws + 8388608;
    unsigned short* xnb  = (unsigned short*)(ws + 11010048);
    unsigned short* wbuf = (unsigned short*)(ws + 15204352);
    float* proj = ws + 16777216;
    float* u    = ws + 50331648;

    const int R = BATCH * LSEQ;             // 16384

    k_embed<<<R, 256, 0, stream>>>(xs, ys, read_in_w, read_in_b, h);

    for (int l = 0; l < NLAYER; ++l) {
        const float* nw  = norm_w    + (size_t)l * HDIM;
        const float* ipw = in_proj_w + (size_t)l * 2048 * 512;
        const float* cw  = conv_w    + (size_t)l * 1024 * 4;
        const float* cb  = conv_b    + (size_t)l * 1024;
        const float* xpw = x_proj_w  + (size_t)l * 160 * 1024;
        const float* dpw = dt_proj_w + (size_t)l * 1024 * 32;
        const float* dpb = dt_proj_b + (size_t)l * 1024;
        const float* al  = A_log     + (size_t)l * 1024 * 64;
        const float* dv  = Dvec      + (size_t)l * 1024;
        const float* opw = out_proj_w+ (size_t)l * 512 * 1024;

        k_wcvt<<<1696, 256, 0, stream>>>(ipw, xpw, opw, wbuf);
        k_rmsnorm<<<R, 256, 0, stream>>>(h, nw, xnb);

        // in_proj: M=16384 N=2048 K=512, A = xnb (bf16)
        k_mgemm<false,false,false><<<dim3(128,16), 256, 0, stream>>>(
            xnb, HDIM, wbuf, proj, 2048, 2048, 512);

        k_conv<<<(R*1024)/256, 256, 0, stream>>>(proj, cw, cb, u);

        // x_proj: M=16384 N=160 K=1024, A = u (fp32 convert)
        k_mgemm<true,false,true><<<dim3(128,2), 256, 0, stream>>>(
            u, 1024, wbuf + 1048576, ssm, 160, 160, 1024);

        // dt_proj: fp32 vector GEMM (K=32, softplus+bias), dt -> proj cols 0..1023
        k_gemm<1,true,false><<<dim3(128,8), 256, 0, stream>>>(
            ssm, 160, dpw, dpb, proj, 2048, 1024, 32);

        k_scan2<<<512, 512, 0, stream>>>(proj, u, ssm, al);

        k_gate<<<(R*1024)/256, 256, 0, stream>>>(proj, u, dv);

        // out_proj: M=16384 N=512 K=1024, A = y in proj (fp32 convert, lda=2048), accumulate into h
        k_mgemm<true,true,false><<<dim3(128,4), 256, 0, stream>>>(
            proj, 2048, wbuf + 1212416, h, HDIM, HDIM, 1024);
    }

    k_head<<<BATCH*KPTS, 256, 0, stream>>>(h, norm_f_w, read_out_w, read_out_b, (float*)d_out);
}